// Round 6
// baseline (423.142 us; speedup 1.0000x reference)
//
#include <hip/hip_runtime.h>
#include <hip/hip_bf16.h>
#include <stdint.h>

#define NB 2
#define NS 4096
#define ND 768
#define NH 12
#define NW 128
#define NDFF 3072
#define NHD 64
#define NCH 32   // NS/NW

typedef __attribute__((ext_vector_type(8))) short bf16x8;
typedef __attribute__((ext_vector_type(4))) short s16x4;
typedef __attribute__((ext_vector_type(4))) float f32x4;
typedef __attribute__((ext_vector_type(4))) int i32x4;

__device__ __forceinline__ float bf2f(short u) {
    union { unsigned int i; float f; } c;
    c.i = ((unsigned int)(unsigned short)u) << 16;
    return c.f;
}
__device__ __forceinline__ short f2bf(float f) {
    union { float f; unsigned int i; } c;
    c.f = f;
    unsigned int x = c.i;
    return (short)((x + 0x7fffu + ((x >> 16) & 1u)) >> 16);
}
__device__ __forceinline__ unsigned int cvtpk(float lo, float hi) {
    unsigned int r;
    asm("v_cvt_pk_bf16_f32 %0, %1, %2" : "=v"(r) : "v"(lo), "v"(hi));
    return r;
}

__device__ __forceinline__ void gl16(const void* g, const void* l) {
    __builtin_amdgcn_global_load_lds(
        (const __attribute__((address_space(1))) void*)g,
        (__attribute__((address_space(3))) void*)l, 16, 0, 0);
}

// ---------------- cast f32 -> bf16 (vectorized) ----------------
__global__ __launch_bounds__(256) void cast_bf16(const float* __restrict__ in,
                                                 short* __restrict__ out, int n4) {
    int i = blockIdx.x * 256 + threadIdx.x;
    if (i < n4) {
        f32x4 v = ((const f32x4*)in)[i];
        s16x4 o;
        o[0] = f2bf(v[0]); o[1] = f2bf(v[1]); o[2] = f2bf(v[2]); o[3] = f2bf(v[3]);
        ((s16x4*)out)[i] = o;
    }
}

// ---------------- transpose + cast: in[K][N] f32 -> out[N][K] bf16 ----------------
__global__ __launch_bounds__(256) void transpose_cast(const float* __restrict__ in,
                                                      short* __restrict__ out,
                                                      int K, int N) {
    __shared__ float tile[32][33];
    int kb = blockIdx.y * 32, nb = blockIdx.x * 32;
    int tx = threadIdx.x & 31, ty = threadIdx.x >> 5;   // ty 0..7
    #pragma unroll
    for (int r = ty; r < 32; r += 8)
        tile[r][tx] = in[(long)(kb + r) * N + nb + tx];
    __syncthreads();
    #pragma unroll
    for (int r = ty; r < 32; r += 8)
        out[(long)(nb + r) * K + kb + tx] = f2bf(tile[tx][r]);
}

// ------------- 128x128 double-buffered GEMM: C = A[M][K] @ Bt[N][K]^T -------------
// (structure unchanged from Round 4 — verified working; MODE 3 residual now bf16)
template<int MODE>
__global__ __launch_bounds__(256, 2) void gemmdb(
    const short* __restrict__ A,
    const short* __restrict__ Bt,
    const float* __restrict__ b0,
    const float* __restrict__ b1,
    const float* __restrict__ b2,
    void* __restrict__ outp,
    const short* __restrict__ xres,
    int M, int N, int K, int gx)
{
    __shared__ short lds[2][256 * 64];   // per buf: A[128][64] | B[128][64]
    const int KT = K >> 6;

    int cpx = gridDim.x >> 3;
    int bid = blockIdx.x;
    int tile = (bid & 7) * cpx + (bid >> 3);
    int n0 = (tile % gx) * 128;
    int m0 = (tile / gx) * 128;

    int tid = threadIdx.x;
    int wid = tid >> 6, lane = tid & 63;
    int wr = wid >> 1, wc = wid & 1;          // 2x2 waves, wave tile 64x64
    int g = lane >> 4, lr = lane & 15;

    int rl = lane >> 3, sl = lane & 7;
    int soff = (sl ^ rl) << 3;                 // k-element offset (swizzled)
    const short* gA[4];
    const short* gB[4];
    #pragma unroll
    for (int c = 0; c < 4; ++c) {
        int row = c * 32 + wid * 8 + rl;
        gA[c] = A + (long)(m0 + row) * K + soff;
        gB[c] = Bt + (long)(n0 + row) * K + soff;
    }

    f32x4 acc[4][4];
    #pragma unroll
    for (int a = 0; a < 4; ++a)
        #pragma unroll
        for (int c = 0; c < 4; ++c)
            acc[a][c] = (f32x4){0.f, 0.f, 0.f, 0.f};

    auto stage = [&](int t, int buf) {
        long ko = (long)t << 6;
        #pragma unroll
        for (int c = 0; c < 4; ++c) {
            int lbase = (c * 32 + wid * 8) * 64;
            gl16(gA[c] + ko, &lds[buf][lbase]);
            gl16(gB[c] + ko, &lds[buf][128 * 64 + lbase]);
        }
    };

    stage(0, 0);
    asm volatile("s_waitcnt vmcnt(0)" ::: "memory");
    __builtin_amdgcn_s_barrier();

    int buf = 0;
    for (int t = 0; t < KT; ++t) {
        if (t + 1 < KT) stage(t + 1, buf ^ 1);
        const short* bufA = lds[buf];
        const short* bufB = lds[buf] + 128 * 64;
        bf16x8 af[2][4], bfr[2][4];
        #pragma unroll
        for (int kk = 0; kk < 2; ++kk) {
            int ph = (((kk << 2) + g) ^ (lr & 7)) << 3;   // swizzled k-slot (elems)
            #pragma unroll
            for (int mt = 0; mt < 4; ++mt)
                af[kk][mt] = *(const bf16x8*)&bufA[(wr * 64 + mt * 16 + lr) * 64 + ph];
            #pragma unroll
            for (int nt = 0; nt < 4; ++nt)
                bfr[kk][nt] = *(const bf16x8*)&bufB[(wc * 64 + nt * 16 + lr) * 64 + ph];
        }
        #pragma unroll
        for (int kk = 0; kk < 2; ++kk)
            #pragma unroll
            for (int mt = 0; mt < 4; ++mt)
                #pragma unroll
                for (int nt = 0; nt < 4; ++nt)
                    acc[mt][nt] = __builtin_amdgcn_mfma_f32_16x16x32_bf16(
                        af[kk][mt], bfr[kk][nt], acc[mt][nt], 0, 0, 0);
        asm volatile("s_waitcnt vmcnt(0)" ::: "memory");
        __builtin_amdgcn_s_barrier();
        buf ^= 1;
    }

    // ---- epilogue
    int mr0 = m0 + wr * 64;
    int nc0 = n0 + wc * 64;
    if (MODE == 4) {
        int proj = n0 / 768;   // 0=q,1=k,2=v
        const float* bp = (proj == 0) ? b0 : (proj == 1) ? b1 : b2;
        float scl = (proj == 0) ? 0.125f : 1.0f;
        short* obase = (short*)outp + (long)proj * ((long)NB * NS * ND);
        #pragma unroll
        for (int mt = 0; mt < 4; ++mt) {
            #pragma unroll
            for (int nt = 0; nt < 4; ++nt) {
                int c = nc0 + nt * 16 + lr - proj * 768;
                int hh = c >> 6, hd = c & 63;
                float bv = bp[c];
                if (proj == 2) {
                    int m = mr0 + mt * 16 + (g << 2);
                    int bbi = m >> 12, s = m & (NS - 1);
                    s16x4 ov;
                    ov[0] = f2bf(acc[mt][nt][0] + bv);
                    ov[1] = f2bf(acc[mt][nt][1] + bv);
                    ov[2] = f2bf(acc[mt][nt][2] + bv);
                    ov[3] = f2bf(acc[mt][nt][3] + bv);
                    *(s16x4*)&obase[((long)(bbi * NH + hh) * NHD + hd) * NS + s] = ov;
                } else {
                    #pragma unroll
                    for (int i = 0; i < 4; ++i) {
                        int m = mr0 + mt * 16 + (g << 2) + i;
                        int bbi = m >> 12, s = m & (NS - 1);
                        obase[((long)(bbi * NH + hh) * NS + s) * NHD + hd] =
                            f2bf((acc[mt][nt][i] + bv) * scl);
                    }
                }
            }
        }
    } else {
        #pragma unroll
        for (int mt = 0; mt < 4; ++mt) {
            #pragma unroll
            for (int nt = 0; nt < 4; ++nt) {
                int col = nc0 + nt * 16 + lr;
                float bv = b0[col];
                #pragma unroll
                for (int i = 0; i < 4; ++i) {
                    int m = mr0 + mt * 16 + (g << 2) + i;
                    float v = acc[mt][nt][i];
                    if (MODE == 2) {
                        v = fmaxf(v + bv, 0.f);
                        ((short*)outp)[(long)m * NDFF + col] = f2bf(v);
                    } else {
                        v = v + bv + bf2f(xres[(long)m * ND + col]);
                        ((float*)outp)[(long)m * ND + col] = v;
                    }
                }
            }
        }
    }
}

// ---------------- band attention (swapped-QK, register P, 54 KB LDS) ----------------
#define KLD 72    // 64 + 8 pad (bf16)
#define PLD 392   // Vt row stride
#define ATT_LDS (384 * KLD * 2)   // 55296 B -> 2 blocks/CU

__global__ __launch_bounds__(512, 8) void attn_kernel(
    const short* __restrict__ qg,   // (B,H,S,HD) bf16, pre-scaled
    const short* __restrict__ kg,   // (B,H,S,HD) bf16
    const short* __restrict__ vtg,  // (B,H,HD,S) bf16
    const float* __restrict__ src,  // (B,S,D) f32
    float* __restrict__ attw,       // (B,H,S,257) f32
    short* __restrict__ xb)         // (B,S,D) bf16
{
    extern __shared__ char smem[];
    short* kv = (short*)smem;       // K tile [384][KLD]; later Vt [64][PLD]

    int blk = blockIdx.x;
    int ch = blk & 31;
    int tmp = blk >> 5;
    int h = tmp % NH;
    int b = tmp / NH;
    int tid = threadIdx.x;
    int wid = tid >> 6;
    int lane = tid & 63;
    int g = lane >> 4, lr = lane & 15;
    long bh = (long)(b * NH + h);
    long kbase = bh * NS * NHD;
    int srow0 = ch * NW;

    // stage K rows j=0..383 (key pos = srow0-128+j), zero-fill OOB
    #pragma unroll
    for (int it = 0; it < 6; ++it) {
        int idx = it * 512 + tid;
        int j = idx >> 3;
        int c = (idx & 7) << 3;
        int s = srow0 - NW + j;
        bf16x8 v = {};
        if (s >= 0 && s < NS)
            v = *(const bf16x8*)&kg[kbase + (long)s * NHD + c];
        *(bf16x8*)&kv[j * KLD + c] = v;
    }

    // T14: V -> regs now; ds_write after QK reads finish
    bf16x8 vreg[6];
    #pragma unroll
    for (int it = 0; it < 6; ++it) {
        int idx = it * 512 + tid;
        int hd = idx / 48;
        int c = (idx % 48) << 3;
        int s0 = srow0 - NW + c;
        bf16x8 v = {};
        if (s0 >= 0 && s0 < NS)
            v = *(const bf16x8*)&vtg[(bh * NHD + hd) * NS + s0];
        vreg[it] = v;
    }

    // Q fragments (B-operand of swapped QK): row t = t0 + lr
    int t0 = wid << 4;
    int tl = t0 + lr;                 // this lane's q-row (local)
    bf16x8 aq[2];
    #pragma unroll
    for (int kk = 0; kk < 2; ++kk)
        aq[kk] = *(const bf16x8*)&qg[kbase + (long)(srow0 + tl) * NHD + (kk << 5) + (g << 3)];

    // sync1: K visible (lgkm only; V reg-loads stay in flight)
    asm volatile("s_waitcnt lgkmcnt(0)" ::: "memory");
    __builtin_amdgcn_s_barrier();
    __builtin_amdgcn_sched_barrier(0);

    // swapped QK^T: sc[jt] reg i = S[j = jt*16 + 4g + i][t = tl]
    f32x4 sc[24];
    #pragma unroll
    for (int jt = 0; jt < 24; ++jt) {
        f32x4 a = (f32x4){0.f, 0.f, 0.f, 0.f};
        #pragma unroll
        for (int kk = 0; kk < 2; ++kk) {
            bf16x8 bk = *(const bf16x8*)&kv[(jt * 16 + lr) * KLD + (kk << 5) + (g << 3)];
            a = __builtin_amdgcn_mfma_f32_16x16x32_bf16(bk, aq[kk], a, 0, 0, 0);
        }
        sc[jt] = a;
    }

    // mask + row max (row tl; j varies per reg/lane; row spread over 4 g-lanes)
    float mx = -3.0e30f;
    #pragma unroll
    for (int jt = 0; jt < 24; ++jt) {
        int j0 = jt * 16 + (g << 2);
        #pragma unroll
        for (int i = 0; i < 4; ++i) {
            int j = j0 + i;
            int sp = srow0 - NW + j;
            bool ok = (sp >= 0) && (sp < NS) && (j >= tl) && (j <= tl + 2 * NW);
            float v = ok ? sc[jt][i] : -3.0e30f;
            sc[jt][i] = v;
            mx = fmaxf(mx, v);
        }
    }
    mx = fmaxf(mx, __shfl_xor(mx, 16, 64));
    mx = fmaxf(mx, __shfl_xor(mx, 32, 64));
    float sm = 0.f;
    #pragma unroll
    for (int jt = 0; jt < 24; ++jt) {
        #pragma unroll
        for (int i = 0; i < 4; ++i) {
            float v = sc[jt][i];
            float p = (v > -1.0e30f) ? __expf(v - mx) : 0.0f;
            sc[jt][i] = p;
            sm += p;
        }
    }
    sm += __shfl_xor(sm, 16, 64);
    sm += __shfl_xor(sm, 32, 64);
    float inv = 1.0f / sm;

    // normalize, write attn_w (aligned f32x4 fast path), pack bf16 pairs
    unsigned int pku[24][2];
    long awrow = (bh * NS + srow0 + tl) * 257;
    #pragma unroll
    for (int jt = 0; jt < 24; ++jt) {
        float pn[4];
        #pragma unroll
        for (int i = 0; i < 4; ++i) pn[i] = sc[jt][i] * inv;
        int c0 = jt * 16 + (g << 2) - tl;
        if (c0 >= 0 && c0 <= 2 * NW - 3) {
            f32x4 vv = {pn[0], pn[1], pn[2], pn[3]};
            *(f32x4*)&attw[awrow + c0] = vv;   // (awrow+c0) % 4 == 0 -> 16B aligned
        } else {
            #pragma unroll
            for (int i = 0; i < 4; ++i) {
                int c = c0 + i;
                if (c >= 0 && c <= 2 * NW)
                    attw[awrow + c] = pn[i];
            }
        }
        pku[jt][0] = cvtpk(pn[0], pn[1]);
        pku[jt][1] = cvtpk(pn[2], pn[3]);
    }

    // sync2: all QK reads of kv done -> safe to overlay V (lgkm only)
    asm volatile("s_waitcnt lgkmcnt(0)" ::: "memory");
    __builtin_amdgcn_s_barrier();
    __builtin_amdgcn_sched_barrier(0);

    // V: regs -> LDS [64][PLD]
    #pragma unroll
    for (int it = 0; it < 6; ++it) {
        int idx = it * 512 + tid;
        int hd = idx / 48;
        int c = (idx % 48) << 3;
        *(bf16x8*)&kv[hd * PLD + c] = vreg[it];
    }

    // sync3: V visible (lgkm only; attn_w stores still draining)
    asm volatile("s_waitcnt lgkmcnt(0)" ::: "memory");
    __builtin_amdgcn_s_barrier();
    __builtin_amdgcn_sched_barrier(0);

    // PV: A-frags assembled in-register via shfl redistribution.
    // lane (g,lr) needs P[tl][kt*32+8g+u], u=0..7 = pairs from lanes
    // lA = (2*(g&1))*16+lr and lB = lA+16, at jt = 2kt+(g>>1).
    int lA = ((g & 1) << 5) + lr;
    int lB = lA + 16;
    bool hi = (g & 2) != 0;
    f32x4 o[4];
    #pragma unroll
    for (int nt = 0; nt < 4; ++nt) o[nt] = (f32x4){0.f, 0.f, 0.f, 0.f};
    #pragma unroll
    for (int kt = 0; kt < 12; ++kt) {
        int a0 = __shfl((int)pku[2 * kt][0], lA, 64);
        int a1 = __shfl((int)pku[2 * kt][1], lA, 64);
        int a2 = __shfl((int)pku[2 * kt][0], lB, 64);
        int a3 = __shfl((int)pku[2 * kt][1], lB, 64);
        int b0 = __shfl((int)pku[2 * kt + 1][0], lA, 64);
        int b1 = __shfl((int)pku[2 * kt + 1][1], lA, 64);
        int b2 = __shfl((int)pku[2 * kt + 1][0], lB, 64);
        int b3 = __shfl((int)pku[2 * kt + 1][1], lB, 64);
        i32x4 wi;
        wi[0] = hi ? b0 : a0;
        wi[1] = hi ? b1 : a1;
        wi[2] = hi ? b2 : a2;
        wi[3] = hi ? b3 : a3;
        bf16x8 af = *(bf16x8*)&wi;
        #pragma unroll
        for (int nt = 0; nt < 4; ++nt) {
            bf16x8 bv = *(const bf16x8*)&kv[(nt * 16 + lr) * PLD + (kt << 5) + (g << 3)];
            o[nt] = __builtin_amdgcn_mfma_f32_16x16x32_bf16(af, bv, o[nt], 0, 0, 0);
        }
    }

    // x = src + context -> bf16 only
    #pragma unroll
    for (int nt = 0; nt < 4; ++nt) {
        int d = nt * 16 + lr;
        int dcol = h * NHD + d;
        #pragma unroll
        for (int i = 0; i < 4; ++i) {
            int t = t0 + (g << 2) + i;
            long row = (long)b * NS + srow0 + t;
            float v = o[nt][i] + src[row * ND + dcol];
            xb[row * ND + dcol] = f2bf(v);
        }
    }
}

// ---------------- layernorm (in-place on y) ----------------
__global__ __launch_bounds__(256) void ln_kernel(float* __restrict__ y,
                                                 const float* __restrict__ g2,
                                                 const float* __restrict__ beta2) {
    int row = blockIdx.x;
    long base = (long)row * ND;
    int tid = threadIdx.x;
    float v[3];
    float s = 0.f, ss = 0.f;
    #pragma unroll
    for (int i = 0; i < 3; ++i) {
        v[i] = y[base + i * 256 + tid];
        s += v[i];
        ss += v[i] * v[i];
    }
    #pragma unroll
    for (int m = 1; m < 64; m <<= 1) {
        s += __shfl_xor(s, m, 64);
        ss += __shfl_xor(ss, m, 64);
    }
    __shared__ float red[8];
    int wid = tid >> 6, lane = tid & 63;
    if (lane == 0) { red[wid] = s; red[wid + 4] = ss; }
    __syncthreads();
    s = red[0] + red[1] + red[2] + red[3];
    ss = red[4] + red[5] + red[6] + red[7];
    float mu = s * (1.0f / ND);
    float var = ss * (1.0f / ND) - mu * mu;
    float rstd = rsqrtf(var + 1e-6f);
    #pragma unroll
    for (int i = 0; i < 3; ++i) {
        int c = i * 256 + tid;
        y[base + c] = g2[c] * (v[i] - mu) * rstd + beta2[c];
    }
}

extern "C" void kernel_launch(void* const* d_in, const int* in_sizes, int n_in,
                              void* d_out, int out_size, void* d_ws, size_t ws_size,
                              hipStream_t stream) {
    const float* src  = (const float*)d_in[0];
    const float* Wq   = (const float*)d_in[1];
    const float* bq   = (const float*)d_in[2];
    const float* Wk   = (const float*)d_in[3];
    const float* bk   = (const float*)d_in[4];
    const float* Wv   = (const float*)d_in[5];
    const float* bv   = (const float*)d_in[6];
    const float* W1   = (const float*)d_in[7];
    const float* b1   = (const float*)d_in[8];
    const float* W2   = (const float*)d_in[9];
    const float* b2   = (const float*)d_in[10];
    const float* g2   = (const float*)d_in[11];
    const float* bt2  = (const float*)d_in[12];

    float* out  = (float*)d_out;                       // y, then LN result in-place
    float* attw = out + (long)NB * NS * ND;

    char* ws = (char*)d_ws;
    const size_t SZ_XF  = (size_t)NB * NS * ND * 4;    // (unused pad, keeps layout)
    const size_t SZ_XB  = (size_t)NB * NS * ND * 2;
    const size_t SZ_W1T = (size_t)ND * NDFF * 2;
    const size_t SZ_W2T = (size_t)NDFF * ND * 2;
    const size_t SZ_QKV = (size_t)NB * NS * ND * 2;
    const size_t SZ_WT  = (size_t)ND * ND * 2;

    short* x_bf  = (short*)(ws + SZ_XF);
    short* W1T   = (short*)(ws + SZ_XF + SZ_XB);
    short* W2T   = (short*)(ws + SZ_XF + SZ_XB + SZ_W1T);
    char*  regA  = ws + SZ_XF + SZ_XB + SZ_W1T + SZ_W2T;
    short* srcb  = (short*)regA;
    short* WqT   = (short*)(regA + SZ_QKV);            // rows 0..767   }  contiguous
    short* WkT   = (short*)(regA + SZ_QKV + SZ_WT);    // rows 768..1535}  Wqkv^T
    short* WvT   = (short*)(regA + SZ_QKV + 2 * SZ_WT);// rows 1536..2303} [2304][768]
    short* qb    = (short*)(regA + SZ_QKV + 3 * SZ_WT);
    short* kb_   = (short*)(regA + 2 * SZ_QKV + 3 * SZ_WT);
    short* vb_   = (short*)(regA + 3 * SZ_QKV + 3 * SZ_WT);
    short* hbuf  = (short*)regA;   // aliases srcb..vb_ (dead after attention)

    const int M = NB * NS;   // 8192

    // casts / transposes
    cast_bf16<<<(M * ND / 4 + 255) / 256, 256, 0, stream>>>(src, srcb, M * ND / 4);
    transpose_cast<<<dim3(ND / 32, ND / 32), 256, 0, stream>>>(Wq, WqT, ND, ND);
    transpose_cast<<<dim3(ND / 32, ND / 32), 256, 0, stream>>>(Wk, WkT, ND, ND);
    transpose_cast<<<dim3(ND / 32, ND / 32), 256, 0, stream>>>(Wv, WvT, ND, ND);
    transpose_cast<<<dim3(NDFF / 32, ND / 32), 256, 0, stream>>>(W1, W1T, ND, NDFF);
    transpose_cast<<<dim3(ND / 32, NDFF / 32), 256, 0, stream>>>(W2, W2T, NDFF, ND);

    // fused QKV projection (N = 2304 = q|k|v), grid 18*64 = 1152 (div by 8)
    gemmdb<4><<<(2304 / 128) * (M / 128), 256, 0, stream>>>(
        srcb, WqT, bq, bk, bv, qb, nullptr, M, 2304, ND, 2304 / 128);

    // band attention
    (void)hipFuncSetAttribute(reinterpret_cast<const void*>(attn_kernel),
                              hipFuncAttributeMaxDynamicSharedMemorySize, ATT_LDS);
    attn_kernel<<<NB * NH * NCH, 512, ATT_LDS, stream>>>(qb, kb_, vb_, src, attw, x_bf);

    // FFN: grids 24*64 = 1536 and 6*64 = 384 (both div by 8)
    gemmdb<2><<<(NDFF / 128) * (M / 128), 256, 0, stream>>>(
        x_bf, W1T, b1, b1, b1, hbuf, nullptr, M, NDFF, ND, NDFF / 128);
    gemmdb<3><<<(ND / 128) * (M / 128), 256, 0, stream>>>(
        hbuf, W2T, b2, b2, b2, out, x_bf, M, ND, NDFF, ND / 128);

    // LayerNorm in-place
    ln_kernel<<<M, 256, 0, stream>>>(out, g2, bt2);
}

// Round 7
// 297.392 us; speedup vs baseline: 1.4228x; 1.4228x over previous
//
#include <hip/hip_runtime.h>
#include <hip/hip_bf16.h>
#include <stdint.h>

#define NB 2
#define NS 4096
#define ND 768
#define NH 12
#define NW 128
#define NDFF 3072
#define NHD 64
#define NCH 32   // NS/NW

typedef __attribute__((ext_vector_type(8))) short bf16x8;
typedef __attribute__((ext_vector_type(4))) short s16x4;
typedef __attribute__((ext_vector_type(4))) float f32x4;
typedef __attribute__((ext_vector_type(4))) int i32x4;

__device__ __forceinline__ float bf2f(short u) {
    union { unsigned int i; float f; } c;
    c.i = ((unsigned int)(unsigned short)u) << 16;
    return c.f;
}
__device__ __forceinline__ short f2bf(float f) {
    union { float f; unsigned int i; } c;
    c.f = f;
    unsigned int x = c.i;
    return (short)((x + 0x7fffu + ((x >> 16) & 1u)) >> 16);
}
__device__ __forceinline__ unsigned int cvtpk(float lo, float hi) {
    unsigned int r;
    asm("v_cvt_pk_bf16_f32 %0, %1, %2" : "=v"(r) : "v"(lo), "v"(hi));
    return r;
}
__device__ __forceinline__ float ubits_lo(unsigned u) {
    union { unsigned i; float f; } c; c.i = u << 16; return c.f;
}
__device__ __forceinline__ float ubits_hi(unsigned u) {
    union { unsigned i; float f; } c; c.i = u & 0xffff0000u; return c.f;
}

__device__ __forceinline__ void gl16(const void* g, const void* l) {
    __builtin_amdgcn_global_load_lds(
        (const __attribute__((address_space(1))) void*)g,
        (__attribute__((address_space(3))) void*)l, 16, 0, 0);
}

// ---------------- cast f32 -> bf16 (vectorized) ----------------
__global__ __launch_bounds__(256) void cast_bf16(const float* __restrict__ in,
                                                 short* __restrict__ out, int n4) {
    int i = blockIdx.x * 256 + threadIdx.x;
    if (i < n4) {
        f32x4 v = ((const f32x4*)in)[i];
        s16x4 o;
        o[0] = f2bf(v[0]); o[1] = f2bf(v[1]); o[2] = f2bf(v[2]); o[3] = f2bf(v[3]);
        ((s16x4*)out)[i] = o;
    }
}

// ---------------- transpose + cast: in[K][N] f32 -> out[N][K] bf16 ----------------
__global__ __launch_bounds__(256) void transpose_cast(const float* __restrict__ in,
                                                      short* __restrict__ out,
                                                      int K, int N) {
    __shared__ float tile[32][33];
    int kb = blockIdx.y * 32, nb = blockIdx.x * 32;
    int tx = threadIdx.x & 31, ty = threadIdx.x >> 5;   // ty 0..7
    #pragma unroll
    for (int r = ty; r < 32; r += 8)
        tile[r][tx] = in[(long)(kb + r) * N + nb + tx];
    __syncthreads();
    #pragma unroll
    for (int r = ty; r < 32; r += 8)
        out[(long)(nb + r) * K + kb + tx] = f2bf(tile[tx][r]);
}

// ------------- 128x128 double-buffered GEMM (unchanged, verified) -------------
template<int MODE>
__global__ __launch_bounds__(256, 2) void gemmdb(
    const short* __restrict__ A,
    const short* __restrict__ Bt,
    const float* __restrict__ b0,
    const float* __restrict__ b1,
    const float* __restrict__ b2,
    void* __restrict__ outp,
    const short* __restrict__ xres,
    int M, int N, int K, int gx)
{
    __shared__ short lds[2][256 * 64];   // per buf: A[128][64] | B[128][64]
    const int KT = K >> 6;

    int cpx = gridDim.x >> 3;
    int bid = blockIdx.x;
    int tile = (bid & 7) * cpx + (bid >> 3);
    int n0 = (tile % gx) * 128;
    int m0 = (tile / gx) * 128;

    int tid = threadIdx.x;
    int wid = tid >> 6, lane = tid & 63;
    int wr = wid >> 1, wc = wid & 1;          // 2x2 waves, wave tile 64x64
    int g = lane >> 4, lr = lane & 15;

    int rl = lane >> 3, sl = lane & 7;
    int soff = (sl ^ rl) << 3;                 // k-element offset (swizzled)
    const short* gA[4];
    const short* gB[4];
    #pragma unroll
    for (int c = 0; c < 4; ++c) {
        int row = c * 32 + wid * 8 + rl;
        gA[c] = A + (long)(m0 + row) * K + soff;
        gB[c] = Bt + (long)(n0 + row) * K + soff;
    }

    f32x4 acc[4][4];
    #pragma unroll
    for (int a = 0; a < 4; ++a)
        #pragma unroll
        for (int c = 0; c < 4; ++c)
            acc[a][c] = (f32x4){0.f, 0.f, 0.f, 0.f};

    auto stage = [&](int t, int buf) {
        long ko = (long)t << 6;
        #pragma unroll
        for (int c = 0; c < 4; ++c) {
            int lbase = (c * 32 + wid * 8) * 64;
            gl16(gA[c] + ko, &lds[buf][lbase]);
            gl16(gB[c] + ko, &lds[buf][128 * 64 + lbase]);
        }
    };

    stage(0, 0);
    asm volatile("s_waitcnt vmcnt(0)" ::: "memory");
    __builtin_amdgcn_s_barrier();

    int buf = 0;
    for (int t = 0; t < KT; ++t) {
        if (t + 1 < KT) stage(t + 1, buf ^ 1);
        const short* bufA = lds[buf];
        const short* bufB = lds[buf] + 128 * 64;
        bf16x8 af[2][4], bfr[2][4];
        #pragma unroll
        for (int kk = 0; kk < 2; ++kk) {
            int ph = (((kk << 2) + g) ^ (lr & 7)) << 3;   // swizzled k-slot (elems)
            #pragma unroll
            for (int mt = 0; mt < 4; ++mt)
                af[kk][mt] = *(const bf16x8*)&bufA[(wr * 64 + mt * 16 + lr) * 64 + ph];
            #pragma unroll
            for (int nt = 0; nt < 4; ++nt)
                bfr[kk][nt] = *(const bf16x8*)&bufB[(wc * 64 + nt * 16 + lr) * 64 + ph];
        }
        #pragma unroll
        for (int kk = 0; kk < 2; ++kk)
            #pragma unroll
            for (int mt = 0; mt < 4; ++mt)
                #pragma unroll
                for (int nt = 0; nt < 4; ++nt)
                    acc[mt][nt] = __builtin_amdgcn_mfma_f32_16x16x32_bf16(
                        af[kk][mt], bfr[kk][nt], acc[mt][nt], 0, 0, 0);
        asm volatile("s_waitcnt vmcnt(0)" ::: "memory");
        __builtin_amdgcn_s_barrier();
        buf ^= 1;
    }

    // ---- epilogue
    int mr0 = m0 + wr * 64;
    int nc0 = n0 + wc * 64;
    if (MODE == 4) {
        int proj = n0 / 768;   // 0=q,1=k,2=v
        const float* bp = (proj == 0) ? b0 : (proj == 1) ? b1 : b2;
        float scl = (proj == 0) ? 0.125f : 1.0f;
        short* obase = (short*)outp + (long)proj * ((long)NB * NS * ND);
        #pragma unroll
        for (int mt = 0; mt < 4; ++mt) {
            #pragma unroll
            for (int nt = 0; nt < 4; ++nt) {
                int c = nc0 + nt * 16 + lr - proj * 768;
                int hh = c >> 6, hd = c & 63;
                float bv = bp[c];
                if (proj == 2) {
                    int m = mr0 + mt * 16 + (g << 2);
                    int bbi = m >> 12, s = m & (NS - 1);
                    s16x4 ov;
                    ov[0] = f2bf(acc[mt][nt][0] + bv);
                    ov[1] = f2bf(acc[mt][nt][1] + bv);
                    ov[2] = f2bf(acc[mt][nt][2] + bv);
                    ov[3] = f2bf(acc[mt][nt][3] + bv);
                    *(s16x4*)&obase[((long)(bbi * NH + hh) * NHD + hd) * NS + s] = ov;
                } else {
                    #pragma unroll
                    for (int i = 0; i < 4; ++i) {
                        int m = mr0 + mt * 16 + (g << 2) + i;
                        int bbi = m >> 12, s = m & (NS - 1);
                        obase[((long)(bbi * NH + hh) * NS + s) * NHD + hd] =
                            f2bf((acc[mt][nt][i] + bv) * scl);
                    }
                }
            }
        }
    } else {
        #pragma unroll
        for (int mt = 0; mt < 4; ++mt) {
            #pragma unroll
            for (int nt = 0; nt < 4; ++nt) {
                int col = nc0 + nt * 16 + lr;
                float bv = b0[col];
                #pragma unroll
                for (int i = 0; i < 4; ++i) {
                    int m = mr0 + mt * 16 + (g << 2) + i;
                    float v = acc[mt][nt][i];
                    if (MODE == 2) {
                        v = fmaxf(v + bv, 0.f);
                        ((short*)outp)[(long)m * NDFF + col] = f2bf(v);
                    } else {
                        v = v + bv + bf2f(xres[(long)m * ND + col]);
                        ((float*)outp)[(long)m * ND + col] = v;
                    }
                }
            }
        }
    }
}

// ------- band attention: swapped-QK, 2-half online softmax, gl16 K/V, 48KB LDS -------
__global__ __launch_bounds__(512, 4) void attn_kernel(
    const short* __restrict__ qg,   // (B,H,S,HD) bf16, pre-scaled
    const short* __restrict__ kg,   // (B,H,S,HD) bf16
    const short* __restrict__ vtg,  // (B,H,HD,S) bf16
    const float* __restrict__ src,  // (B,S,D) f32
    float* __restrict__ attw,       // (B,H,S,257) f32
    short* __restrict__ xb)         // (B,S,D) bf16
{
    __shared__ short kvs[384 * 64];   // 48KB: K [384][64] -> later V [64][384]

    int blk = blockIdx.x;
    int ch = blk & 31;
    int tmp = blk >> 5;
    int h = tmp % NH;
    int b = tmp / NH;
    int tid = threadIdx.x;
    int wid = tid >> 6;
    int lane = tid & 63;
    int g = lane >> 4, lr = lane & 15;
    long bh = (long)(b * NH + h);
    long kbase = bh * NS * NHD;
    int srow0 = ch * NW;
    int t0 = wid << 4;
    int tl = t0 + lr;                 // this lane's q-row (local)

    // ---- K staging via gl16 (rows j 0..383, chunk-XOR swizzled source, clamped) ----
    {
        int rsub = lane >> 3;          // 0..7
        int pc = lane & 7;             // phys chunk
        int lc = pc ^ rsub;            // logical chunk (row&7 == rsub)
        #pragma unroll
        for (int i = 0; i < 6; ++i) {
            int inst = wid * 6 + i;
            int j = inst * 8 + rsub;
            int s = srow0 - NW + j;
            s = s < 0 ? 0 : (s >= NS ? NS - 1 : s);   // garbage rows masked later
            gl16(&kg[kbase + (long)s * NHD + lc * 8], &kvs[inst * 512 + lane * 8]);
        }
    }
    // Q fragments (B-operand of swapped QK)
    bf16x8 aq[2];
    #pragma unroll
    for (int kk = 0; kk < 2; ++kk)
        aq[kk] = *(const bf16x8*)&qg[kbase + (long)(srow0 + tl) * NHD + (kk << 5) + (g << 3)];

    asm volatile("s_waitcnt vmcnt(0)" ::: "memory");
    __builtin_amdgcn_s_barrier();
    __builtin_amdgcn_sched_barrier(0);

    // ---- half score pass: jt in [jtb, jtb+12) ----
    unsigned pku0[12][2], pku1[12][2];
    float m0, s0, m1, s1;
    auto half_pass = [&](int jtb, unsigned (&pk)[12][2], float& mh, float& sh) {
        f32x4 sc[12];
        #pragma unroll
        for (int q = 0; q < 12; ++q) {
            int jt = jtb + q;
            f32x4 a = (f32x4){0.f, 0.f, 0.f, 0.f};
            #pragma unroll
            for (int kk = 0; kk < 2; ++kk) {
                int phys = (((kk << 2) + g) ^ (lr & 7)) << 3;
                bf16x8 bk = *(const bf16x8*)&kvs[(jt * 16 + lr) * 64 + phys];
                a = __builtin_amdgcn_mfma_f32_16x16x32_bf16(bk, aq[kk], a, 0, 0, 0);
            }
            sc[q] = a;
        }
        float mx = -3.0e30f;
        #pragma unroll
        for (int q = 0; q < 12; ++q) {
            int j0 = (jtb + q) * 16 + (g << 2);
            #pragma unroll
            for (int i = 0; i < 4; ++i) {
                int j = j0 + i;
                int sp = srow0 - NW + j;
                bool ok = (sp >= 0) && (sp < NS) && (j >= tl) && (j <= tl + 2 * NW);
                float v = ok ? sc[q][i] : -3.0e30f;
                sc[q][i] = v;
                mx = fmaxf(mx, v);
            }
        }
        mx = fmaxf(mx, __shfl_xor(mx, 16, 64));
        mx = fmaxf(mx, __shfl_xor(mx, 32, 64));
        float sm = 0.f;
        #pragma unroll
        for (int q = 0; q < 12; ++q) {
            #pragma unroll
            for (int i = 0; i < 4; ++i) {
                float v = sc[q][i];
                float p = (v > -1.0e30f) ? __expf(v - mx) : 0.0f;
                sc[q][i] = p;
                sm += p;
            }
            pk[q][0] = cvtpk(sc[q][0], sc[q][1]);
            pk[q][1] = cvtpk(sc[q][2], sc[q][3]);
        }
        sm += __shfl_xor(sm, 16, 64);
        sm += __shfl_xor(sm, 32, 64);
        mh = mx; sh = sm;
    };

    // V staging helper: half hf (0: hd 0..31 over K0 region; 1: hd 32..63 over K1)
    auto stageV = [&](int hf) {
        #pragma unroll
        for (int i = 0; i < 3; ++i) {
            int v = wid * 3 + i;                    // 0..23
            int fc = hf * 1536 + v * 64 + lane;     // flat chunk 0..3071
            int hd = fc / 48;
            int pc = fc % 48;
            int lc = (pc & ~7) | ((pc & 7) ^ (hd & 7));
            int scol = srow0 - NW + lc * 8;
            scol = scol < 0 ? 0 : (scol > NS - 8 ? NS - 8 : scol);
            gl16(&vtg[(bh * NHD + hd) * NS + scol],
                 &kvs[hf * 12288 + v * 512 + lane * 8]);
        }
    };

    half_pass(0, pku0, m0, s0);
    asm volatile("s_waitcnt lgkmcnt(0)" ::: "memory");
    __builtin_amdgcn_s_barrier();        // K rows 0..191 free
    __builtin_amdgcn_sched_barrier(0);
    stageV(0);                            // hides under half 1

    half_pass(12, pku1, m1, s1);
    asm volatile("s_waitcnt lgkmcnt(0)" ::: "memory");
    __builtin_amdgcn_s_barrier();        // K rows 192..383 free
    __builtin_amdgcn_sched_barrier(0);
    stageV(1);

    // ---- merge halves, normalize packed P ----
    float m = fmaxf(m0, m1);
    float r0 = __expf(m0 - m), r1 = __expf(m1 - m);
    float inv = 1.0f / (s0 * r0 + s1 * r1);
    float w0 = r0 * inv, w1 = r1 * inv;
    #pragma unroll
    for (int q = 0; q < 12; ++q) {
        #pragma unroll
        for (int u = 0; u < 2; ++u) {
            pku0[q][u] = cvtpk(ubits_lo(pku0[q][u]) * w0, ubits_hi(pku0[q][u]) * w0);
            pku1[q][u] = cvtpk(ubits_lo(pku1[q][u]) * w1, ubits_hi(pku1[q][u]) * w1);
        }
    }

    // ---- build PV A-fragments in-register (shfl redistribution, as verified R6) ----
    int lA = ((g & 1) << 5) + lr;
    int lB = lA + 16;
    bool hi_ = (g & 2) != 0;
    i32x4 af_[12];
    auto build = [&](int kt, const unsigned (&pa)[2], const unsigned (&pb)[2]) {
        int a0 = __shfl((int)pa[0], lA, 64);
        int a1 = __shfl((int)pa[1], lA, 64);
        int a2 = __shfl((int)pa[0], lB, 64);
        int a3 = __shfl((int)pa[1], lB, 64);
        int b0 = __shfl((int)pb[0], lA, 64);
        int b1 = __shfl((int)pb[1], lA, 64);
        int b2 = __shfl((int)pb[0], lB, 64);
        int b3 = __shfl((int)pb[1], lB, 64);
        i32x4 wi;
        wi[0] = hi_ ? b0 : a0;
        wi[1] = hi_ ? b1 : a1;
        wi[2] = hi_ ? b2 : a2;
        wi[3] = hi_ ? b3 : a3;
        af_[kt] = wi;
    };
    #pragma unroll
    for (int kt = 0; kt < 6; ++kt)  build(kt, pku0[2 * kt], pku0[2 * kt + 1]);
    #pragma unroll
    for (int kt = 6; kt < 12; ++kt) build(kt, pku1[2 * kt - 12], pku1[2 * kt - 11]);

    // ---- PV part 1: V0 (rows 0..31, nt=0,1) ----
    asm volatile("s_waitcnt vmcnt(3)" ::: "memory");
    __builtin_amdgcn_s_barrier();
    __builtin_amdgcn_sched_barrier(0);

    f32x4 o[4];
    #pragma unroll
    for (int nt = 0; nt < 4; ++nt) o[nt] = (f32x4){0.f, 0.f, 0.f, 0.f};
    #pragma unroll
    for (int kt = 0; kt < 12; ++kt) {
        bf16x8 af = *(const bf16x8*)&af_[kt];
        #pragma unroll
        for (int nt = 0; nt < 2; ++nt) {
            int c = kt * 4 + g;
            int phys = ((c & ~7) | ((c & 7) ^ (lr & 7))) << 3;
            bf16x8 bv = *(const bf16x8*)&kvs[(nt * 16 + lr) * 384 + phys];
            o[nt] = __builtin_amdgcn_mfma_f32_16x16x32_bf16(af, bv, o[nt], 0, 0, 0);
        }
    }
    // ---- PV part 2: V1 (rows 32..63, nt=2,3) ----
    asm volatile("s_waitcnt vmcnt(0)" ::: "memory");
    __builtin_amdgcn_s_barrier();
    __builtin_amdgcn_sched_barrier(0);
    #pragma unroll
    for (int kt = 0; kt < 12; ++kt) {
        bf16x8 af = *(const bf16x8*)&af_[kt];
        #pragma unroll
        for (int nt = 2; nt < 4; ++nt) {
            int c = kt * 4 + g;
            int phys = ((c & ~7) | ((c & 7) ^ (lr & 7))) << 3;
            bf16x8 bv = *(const bf16x8*)&kvs[(nt * 16 + lr) * 384 + phys];
            o[nt] = __builtin_amdgcn_mfma_f32_16x16x32_bf16(af, bv, o[nt], 0, 0, 0);
        }
    }

    // ---- x = src + context -> bf16 ----
    #pragma unroll
    for (int nt = 0; nt < 4; ++nt) {
        int d = nt * 16 + lr;
        int dcol = h * NHD + d;
        #pragma unroll
        for (int i = 0; i < 4; ++i) {
            int t = t0 + (g << 2) + i;
            long row = (long)b * NS + srow0 + t;
            float v = o[nt][i] + src[row * ND + dcol];
            xb[row * ND + dcol] = f2bf(v);
        }
    }

    // ---- attn_w from af fragments: lane (g,lr) owns j = kt*32+8g+0..7 of row tl ----
    long awrow = (bh * NS + srow0 + tl) * 257;
    #pragma unroll
    for (int kt = 0; kt < 12; ++kt) {
        float pv_[8];
        #pragma unroll
        for (int p = 0; p < 4; ++p) {
            unsigned u = (unsigned)af_[kt][p];
            pv_[2 * p]     = ubits_lo(u);
            pv_[2 * p + 1] = ubits_hi(u);
        }
        int c0 = kt * 32 + (g << 3) - tl;
        if (c0 >= 0 && c0 <= 2 * NW - 7) {
            f32x4 v0 = {pv_[0], pv_[1], pv_[2], pv_[3]};
            f32x4 v1 = {pv_[4], pv_[5], pv_[6], pv_[7]};
            *(f32x4*)&attw[awrow + c0] = v0;       // (awrow+c0) % 4 == 0
            *(f32x4*)&attw[awrow + c0 + 4] = v1;
        } else {
            #pragma unroll
            for (int e = 0; e < 8; ++e) {
                int c = c0 + e;
                if (c >= 0 && c <= 2 * NW)
                    attw[awrow + c] = pv_[e];
            }
        }
    }
}

// ---------------- layernorm (in-place on y) ----------------
__global__ __launch_bounds__(256) void ln_kernel(float* __restrict__ y,
                                                 const float* __restrict__ g2,
                                                 const float* __restrict__ beta2) {
    int row = blockIdx.x;
    long base = (long)row * ND;
    int tid = threadIdx.x;
    float v[3];
    float s = 0.f, ss = 0.f;
    #pragma unroll
    for (int i = 0; i < 3; ++i) {
        v[i] = y[base + i * 256 + tid];
        s += v[i];
        ss += v[i] * v[i];
    }
    #pragma unroll
    for (int m = 1; m < 64; m <<= 1) {
        s += __shfl_xor(s, m, 64);
        ss += __shfl_xor(ss, m, 64);
    }
    __shared__ float red[8];
    int wid = tid >> 6, lane = tid & 63;
    if (lane == 0) { red[wid] = s; red[wid + 4] = ss; }
    __syncthreads();
    s = red[0] + red[1] + red[2] + red[3];
    ss = red[4] + red[5] + red[6] + red[7];
    float mu = s * (1.0f / ND);
    float var = ss * (1.0f / ND) - mu * mu;
    float rstd = rsqrtf(var + 1e-6f);
    #pragma unroll
    for (int i = 0; i < 3; ++i) {
        int c = i * 256 + tid;
        y[base + c] = g2[c] * (v[i] - mu) * rstd + beta2[c];
    }
}

extern "C" void kernel_launch(void* const* d_in, const int* in_sizes, int n_in,
                              void* d_out, int out_size, void* d_ws, size_t ws_size,
                              hipStream_t stream) {
    const float* src  = (const float*)d_in[0];
    const float* Wq   = (const float*)d_in[1];
    const float* bq   = (const float*)d_in[2];
    const float* Wk   = (const float*)d_in[3];
    const float* bk   = (const float*)d_in[4];
    const float* Wv   = (const float*)d_in[5];
    const float* bv   = (const float*)d_in[6];
    const float* W1   = (const float*)d_in[7];
    const float* b1   = (const float*)d_in[8];
    const float* W2   = (const float*)d_in[9];
    const float* b2   = (const float*)d_in[10];
    const float* g2   = (const float*)d_in[11];
    const float* bt2  = (const float*)d_in[12];

    float* out  = (float*)d_out;                       // y, then LN result in-place
    float* attw = out + (long)NB * NS * ND;

    char* ws = (char*)d_ws;
    const size_t SZ_XF  = (size_t)NB * NS * ND * 4;
    const size_t SZ_XB  = (size_t)NB * NS * ND * 2;
    const size_t SZ_W1T = (size_t)ND * NDFF * 2;
    const size_t SZ_W2T = (size_t)NDFF * ND * 2;
    const size_t SZ_QKV = (size_t)NB * NS * ND * 2;
    const size_t SZ_WT  = (size_t)ND * ND * 2;

    short* x_bf  = (short*)(ws + SZ_XF);
    short* W1T   = (short*)(ws + SZ_XF + SZ_XB);
    short* W2T   = (short*)(ws + SZ_XF + SZ_XB + SZ_W1T);
    char*  regA  = ws + SZ_XF + SZ_XB + SZ_W1T + SZ_W2T;
    short* srcb  = (short*)regA;
    short* WqT   = (short*)(regA + SZ_QKV);            // [2304][768] Wqkv^T contiguous
    short* qb    = (short*)(regA + SZ_QKV + 3 * SZ_WT);
    short* kb_   = (short*)(regA + 2 * SZ_QKV + 3 * SZ_WT);
    short* vb_   = (short*)(regA + 3 * SZ_QKV + 3 * SZ_WT);
    short* WkT   = WqT + (size_t)768 * ND;
    short* WvT   = WqT + (size_t)1536 * ND;
    short* hbuf  = (short*)regA;   // aliases srcb..vb_ (dead after attention)

    const int M = NB * NS;   // 8192

    // casts / transposes
    cast_bf16<<<(M * ND / 4 + 255) / 256, 256, 0, stream>>>(src, srcb, M * ND / 4);
    transpose_cast<<<dim3(ND / 32, ND / 32), 256, 0, stream>>>(Wq, WqT, ND, ND);
    transpose_cast<<<dim3(ND / 32, ND / 32), 256, 0, stream>>>(Wk, WkT, ND, ND);
    transpose_cast<<<dim3(ND / 32, ND / 32), 256, 0, stream>>>(Wv, WvT, ND, ND);
    transpose_cast<<<dim3(NDFF / 32, ND / 32), 256, 0, stream>>>(W1, W1T, ND, NDFF);
    transpose_cast<<<dim3(ND / 32, NDFF / 32), 256, 0, stream>>>(W2, W2T, NDFF, ND);

    // fused QKV projection (N = 2304 = q|k|v), grid 18*64 = 1152 (div by 8)
    gemmdb<4><<<(2304 / 128) * (M / 128), 256, 0, stream>>>(
        srcb, WqT, bq, bk, bv, qb, nullptr, M, 2304, ND, 2304 / 128);

    // band attention (static 48KB LDS)
    attn_kernel<<<NB * NH * NCH, 512, 0, stream>>>(qb, kb_, vb_, src, attw, x_bf);

    // FFN: grids 24*64 = 1536 and 6*64 = 384 (both div by 8)
    gemmdb<2><<<(NDFF / 128) * (M / 128), 256, 0, stream>>>(
        x_bf, W1T, b1, b1, b1, hbuf, nullptr, M, NDFF, ND, NDFF / 128);
    gemmdb<3><<<(ND / 128) * (M / 128), 256, 0, stream>>>(
        hbuf, W2T, b2, b2, b2, out, x_bf, M, ND, NDFF, ND / 128);

    // LayerNorm in-place
    ln_kernel<<<M, 256, 0, stream>>>(out, g2, bt2);
}

// Round 8
// 231.304 us; speedup vs baseline: 1.8294x; 1.2857x over previous
//
#include <hip/hip_runtime.h>
#include <hip/hip_bf16.h>
#include <stdint.h>

#define NB 2
#define NS 4096
#define ND 768
#define NH 12
#define NW 128
#define NDFF 3072
#define NHD 64
#define NCH 32   // NS/NW

typedef __attribute__((ext_vector_type(8))) short bf16x8;
typedef __attribute__((ext_vector_type(4))) short s16x4;
typedef __attribute__((ext_vector_type(4))) float f32x4;
typedef __attribute__((ext_vector_type(4))) int i32x4;

__device__ __forceinline__ float bf2f(short u) {
    union { unsigned int i; float f; } c;
    c.i = ((unsigned int)(unsigned short)u) << 16;
    return c.f;
}
__device__ __forceinline__ short f2bf(float f) {
    union { float f; unsigned int i; } c;
    c.f = f;
    unsigned int x = c.i;
    return (short)((x + 0x7fffu + ((x >> 16) & 1u)) >> 16);
}
__device__ __forceinline__ unsigned int cvtpk(float lo, float hi) {
    unsigned int r;
    asm("v_cvt_pk_bf16_f32 %0, %1, %2" : "=v"(r) : "v"(lo), "v"(hi));
    return r;
}
__device__ __forceinline__ float ubits_lo(unsigned u) {
    union { unsigned i; float f; } c; c.i = u << 16; return c.f;
}
__device__ __forceinline__ float ubits_hi(unsigned u) {
    union { unsigned i; float f; } c; c.i = u & 0xffff0000u; return c.f;
}

__device__ __forceinline__ void gl16(const void* g, const void* l) {
    __builtin_amdgcn_global_load_lds(
        (const __attribute__((address_space(1))) void*)g,
        (__attribute__((address_space(3))) void*)l, 16, 0, 0);
}

// ---------------- cast f32 -> bf16 (vectorized) ----------------
__global__ __launch_bounds__(256) void cast_bf16(const float* __restrict__ in,
                                                 short* __restrict__ out, int n4) {
    int i = blockIdx.x * 256 + threadIdx.x;
    if (i < n4) {
        f32x4 v = ((const f32x4*)in)[i];
        s16x4 o;
        o[0] = f2bf(v[0]); o[1] = f2bf(v[1]); o[2] = f2bf(v[2]); o[3] = f2bf(v[3]);
        ((s16x4*)out)[i] = o;
    }
}

// ---------------- transpose + cast: in[K][N] f32 -> out[N][K] bf16 ----------------
__global__ __launch_bounds__(256) void transpose_cast(const float* __restrict__ in,
                                                      short* __restrict__ out,
                                                      int K, int N) {
    __shared__ float tile[32][33];
    int kb = blockIdx.y * 32, nb = blockIdx.x * 32;
    int tx = threadIdx.x & 31, ty = threadIdx.x >> 5;   // ty 0..7
    #pragma unroll
    for (int r = ty; r < 32; r += 8)
        tile[r][tx] = in[(long)(kb + r) * N + nb + tx];
    __syncthreads();
    #pragma unroll
    for (int r = ty; r < 32; r += 8)
        out[(long)(nb + r) * K + kb + tx] = f2bf(tile[tx][r]);
}

// ------------- 128x128 double-buffered GEMM (unchanged, verified) -------------
template<int MODE>
__global__ __launch_bounds__(256, 2) void gemmdb(
    const short* __restrict__ A,
    const short* __restrict__ Bt,
    const float* __restrict__ b0,
    const float* __restrict__ b1,
    const float* __restrict__ b2,
    void* __restrict__ outp,
    const short* __restrict__ xres,
    int M, int N, int K, int gx)
{
    __shared__ short lds[2][256 * 64];   // per buf: A[128][64] | B[128][64]
    const int KT = K >> 6;

    int cpx = gridDim.x >> 3;
    int bid = blockIdx.x;
    int tile = (bid & 7) * cpx + (bid >> 3);
    int n0 = (tile % gx) * 128;
    int m0 = (tile / gx) * 128;

    int tid = threadIdx.x;
    int wid = tid >> 6, lane = tid & 63;
    int wr = wid >> 1, wc = wid & 1;          // 2x2 waves, wave tile 64x64
    int g = lane >> 4, lr = lane & 15;

    int rl = lane >> 3, sl = lane & 7;
    int soff = (sl ^ rl) << 3;                 // k-element offset (swizzled)
    const short* gA[4];
    const short* gB[4];
    #pragma unroll
    for (int c = 0; c < 4; ++c) {
        int row = c * 32 + wid * 8 + rl;
        gA[c] = A + (long)(m0 + row) * K + soff;
        gB[c] = Bt + (long)(n0 + row) * K + soff;
    }

    f32x4 acc[4][4];
    #pragma unroll
    for (int a = 0; a < 4; ++a)
        #pragma unroll
        for (int c = 0; c < 4; ++c)
            acc[a][c] = (f32x4){0.f, 0.f, 0.f, 0.f};

    auto stage = [&](int t, int buf) {
        long ko = (long)t << 6;
        #pragma unroll
        for (int c = 0; c < 4; ++c) {
            int lbase = (c * 32 + wid * 8) * 64;
            gl16(gA[c] + ko, &lds[buf][lbase]);
            gl16(gB[c] + ko, &lds[buf][128 * 64 + lbase]);
        }
    };

    stage(0, 0);
    asm volatile("s_waitcnt vmcnt(0)" ::: "memory");
    __builtin_amdgcn_s_barrier();

    int buf = 0;
    for (int t = 0; t < KT; ++t) {
        if (t + 1 < KT) stage(t + 1, buf ^ 1);
        const short* bufA = lds[buf];
        const short* bufB = lds[buf] + 128 * 64;
        bf16x8 af[2][4], bfr[2][4];
        #pragma unroll
        for (int kk = 0; kk < 2; ++kk) {
            int ph = (((kk << 2) + g) ^ (lr & 7)) << 3;   // swizzled k-slot (elems)
            #pragma unroll
            for (int mt = 0; mt < 4; ++mt)
                af[kk][mt] = *(const bf16x8*)&bufA[(wr * 64 + mt * 16 + lr) * 64 + ph];
            #pragma unroll
            for (int nt = 0; nt < 4; ++nt)
                bfr[kk][nt] = *(const bf16x8*)&bufB[(wc * 64 + nt * 16 + lr) * 64 + ph];
        }
        #pragma unroll
        for (int kk = 0; kk < 2; ++kk)
            #pragma unroll
            for (int mt = 0; mt < 4; ++mt)
                #pragma unroll
                for (int nt = 0; nt < 4; ++nt)
                    acc[mt][nt] = __builtin_amdgcn_mfma_f32_16x16x32_bf16(
                        af[kk][mt], bfr[kk][nt], acc[mt][nt], 0, 0, 0);
        asm volatile("s_waitcnt vmcnt(0)" ::: "memory");
        __builtin_amdgcn_s_barrier();
        buf ^= 1;
    }

    // ---- epilogue
    int mr0 = m0 + wr * 64;
    int nc0 = n0 + wc * 64;
    if (MODE == 4) {
        int proj = n0 / 768;   // 0=q,1=k,2=v
        const float* bp = (proj == 0) ? b0 : (proj == 1) ? b1 : b2;
        float scl = (proj == 0) ? 0.125f : 1.0f;
        short* obase = (short*)outp + (long)proj * ((long)NB * NS * ND);
        #pragma unroll
        for (int mt = 0; mt < 4; ++mt) {
            #pragma unroll
            for (int nt = 0; nt < 4; ++nt) {
                int c = nc0 + nt * 16 + lr - proj * 768;
                int hh = c >> 6, hd = c & 63;
                float bv = bp[c];
                if (proj == 2) {
                    int m = mr0 + mt * 16 + (g << 2);
                    int bbi = m >> 12, s = m & (NS - 1);
                    s16x4 ov;
                    ov[0] = f2bf(acc[mt][nt][0] + bv);
                    ov[1] = f2bf(acc[mt][nt][1] + bv);
                    ov[2] = f2bf(acc[mt][nt][2] + bv);
                    ov[3] = f2bf(acc[mt][nt][3] + bv);
                    *(s16x4*)&obase[((long)(bbi * NH + hh) * NHD + hd) * NS + s] = ov;
                } else {
                    #pragma unroll
                    for (int i = 0; i < 4; ++i) {
                        int m = mr0 + mt * 16 + (g << 2) + i;
                        int bbi = m >> 12, s = m & (NS - 1);
                        obase[((long)(bbi * NH + hh) * NS + s) * NHD + hd] =
                            f2bf((acc[mt][nt][i] + bv) * scl);
                    }
                }
            }
        }
    } else {
        #pragma unroll
        for (int mt = 0; mt < 4; ++mt) {
            #pragma unroll
            for (int nt = 0; nt < 4; ++nt) {
                int col = nc0 + nt * 16 + lr;
                float bv = b0[col];
                #pragma unroll
                for (int i = 0; i < 4; ++i) {
                    int m = mr0 + mt * 16 + (g << 2) + i;
                    float v = acc[mt][nt][i];
                    if (MODE == 2) {
                        v = fmaxf(v + bv, 0.f);
                        ((short*)outp)[(long)m * NDFF + col] = f2bf(v);
                    } else {
                        v = v + bv + bf2f(xres[(long)m * ND + col]);
                        ((float*)outp)[(long)m * ND + col] = v;
                    }
                }
            }
        }
    }
}

// ------- band attention: swapped-QK, 2-half online softmax, gl16 K/V, 48KB LDS -------
// R8: launch_bounds (512,2) (no forced spill); af built+consumed per kt (no af_ array).
__global__ __launch_bounds__(512, 2) void attn_kernel(
    const short* __restrict__ qg,   // (B,H,S,HD) bf16, pre-scaled
    const short* __restrict__ kg,   // (B,H,S,HD) bf16
    const short* __restrict__ vtg,  // (B,H,HD,S) bf16
    const float* __restrict__ src,  // (B,S,D) f32
    float* __restrict__ attw,       // (B,H,S,257) f32
    short* __restrict__ xb)         // (B,S,D) bf16
{
    __shared__ short kvs[384 * 64];   // 48KB: K [384][64] -> later V [64][384]

    int blk = blockIdx.x;
    int ch = blk & 31;
    int tmp = blk >> 5;
    int h = tmp % NH;
    int b = tmp / NH;
    int tid = threadIdx.x;
    int wid = tid >> 6;
    int lane = tid & 63;
    int g = lane >> 4, lr = lane & 15;
    long bh = (long)(b * NH + h);
    long kbase = bh * NS * NHD;
    int srow0 = ch * NW;
    int t0 = wid << 4;
    int tl = t0 + lr;                 // this lane's q-row (local)

    // ---- K staging via gl16 (rows j 0..383, chunk-XOR swizzled source, clamped) ----
    {
        int rsub = lane >> 3;          // 0..7
        int pc = lane & 7;             // phys chunk
        int lc = pc ^ rsub;            // logical chunk (row&7 == rsub)
        #pragma unroll
        for (int i = 0; i < 6; ++i) {
            int inst = wid * 6 + i;
            int j = inst * 8 + rsub;
            int s = srow0 - NW + j;
            s = s < 0 ? 0 : (s >= NS ? NS - 1 : s);   // garbage rows masked later
            gl16(&kg[kbase + (long)s * NHD + lc * 8], &kvs[inst * 512 + lane * 8]);
        }
    }
    // Q fragments (B-operand of swapped QK)
    bf16x8 aq[2];
    #pragma unroll
    for (int kk = 0; kk < 2; ++kk)
        aq[kk] = *(const bf16x8*)&qg[kbase + (long)(srow0 + tl) * NHD + (kk << 5) + (g << 3)];

    asm volatile("s_waitcnt vmcnt(0)" ::: "memory");
    __builtin_amdgcn_s_barrier();
    __builtin_amdgcn_sched_barrier(0);

    // ---- half score pass: jt in [jtb, jtb+12) ----
    unsigned pku0[12][2], pku1[12][2];
    float m0, s0, m1, s1;
    auto half_pass = [&](int jtb, unsigned (&pk)[12][2], float& mh, float& sh) {
        f32x4 sc[12];
        #pragma unroll
        for (int q = 0; q < 12; ++q) {
            int jt = jtb + q;
            f32x4 a = (f32x4){0.f, 0.f, 0.f, 0.f};
            #pragma unroll
            for (int kk = 0; kk < 2; ++kk) {
                int phys = (((kk << 2) + g) ^ (lr & 7)) << 3;
                bf16x8 bk = *(const bf16x8*)&kvs[(jt * 16 + lr) * 64 + phys];
                a = __builtin_amdgcn_mfma_f32_16x16x32_bf16(bk, aq[kk], a, 0, 0, 0);
            }
            sc[q] = a;
        }
        float mx = -3.0e30f;
        #pragma unroll
        for (int q = 0; q < 12; ++q) {
            int j0 = (jtb + q) * 16 + (g << 2);
            #pragma unroll
            for (int i = 0; i < 4; ++i) {
                int j = j0 + i;
                int sp = srow0 - NW + j;
                bool ok = (sp >= 0) && (sp < NS) && (j >= tl) && (j <= tl + 2 * NW);
                float v = ok ? sc[q][i] : -3.0e30f;
                sc[q][i] = v;
                mx = fmaxf(mx, v);
            }
        }
        mx = fmaxf(mx, __shfl_xor(mx, 16, 64));
        mx = fmaxf(mx, __shfl_xor(mx, 32, 64));
        float sm = 0.f;
        #pragma unroll
        for (int q = 0; q < 12; ++q) {
            #pragma unroll
            for (int i = 0; i < 4; ++i) {
                float v = sc[q][i];
                float p = (v > -1.0e30f) ? __expf(v - mx) : 0.0f;
                sc[q][i] = p;
                sm += p;
            }
            pk[q][0] = cvtpk(sc[q][0], sc[q][1]);
            pk[q][1] = cvtpk(sc[q][2], sc[q][3]);
        }
        sm += __shfl_xor(sm, 16, 64);
        sm += __shfl_xor(sm, 32, 64);
        mh = mx; sh = sm;
    };

    // V staging helper: half hf (0: hd 0..31 over K0 region; 1: hd 32..63 over K1)
    auto stageV = [&](int hf) {
        #pragma unroll
        for (int i = 0; i < 3; ++i) {
            int v = wid * 3 + i;                    // 0..23
            int fc = hf * 1536 + v * 64 + lane;     // flat chunk 0..3071
            int hd = fc / 48;
            int pc = fc % 48;
            int lc = (pc & ~7) | ((pc & 7) ^ (hd & 7));
            int scol = srow0 - NW + lc * 8;
            scol = scol < 0 ? 0 : (scol > NS - 8 ? NS - 8 : scol);
            gl16(&vtg[(bh * NHD + hd) * NS + scol],
                 &kvs[hf * 12288 + v * 512 + lane * 8]);
        }
    };

    half_pass(0, pku0, m0, s0);
    asm volatile("s_waitcnt lgkmcnt(0)" ::: "memory");
    __builtin_amdgcn_s_barrier();        // K rows 0..191 free
    __builtin_amdgcn_sched_barrier(0);
    stageV(0);                            // hides under half 1

    half_pass(12, pku1, m1, s1);
    asm volatile("s_waitcnt lgkmcnt(0)" ::: "memory");
    __builtin_amdgcn_s_barrier();        // K rows 192..383 free
    __builtin_amdgcn_sched_barrier(0);
    stageV(1);

    // ---- merge halves, normalize packed P ----
    float m = fmaxf(m0, m1);
    float r0 = __expf(m0 - m), r1 = __expf(m1 - m);
    float inv = 1.0f / (s0 * r0 + s1 * r1);
    float w0 = r0 * inv, w1 = r1 * inv;
    #pragma unroll
    for (int q = 0; q < 12; ++q) {
        #pragma unroll
        for (int u = 0; u < 2; ++u) {
            pku0[q][u] = cvtpk(ubits_lo(pku0[q][u]) * w0, ubits_hi(pku0[q][u]) * w0);
            pku1[q][u] = cvtpk(ubits_lo(pku1[q][u]) * w1, ubits_hi(pku1[q][u]) * w1);
        }
    }

    // ---- all V staged; single wait, then fused build->attw->MFMA per kt ----
    asm volatile("s_waitcnt vmcnt(0)" ::: "memory");
    __builtin_amdgcn_s_barrier();
    __builtin_amdgcn_sched_barrier(0);

    int lA = ((g & 1) << 5) + lr;
    int lB = lA + 16;
    bool hi_ = (g & 2) != 0;
    long awrow = (bh * NS + srow0 + tl) * 257;
    f32x4 o[4];
    #pragma unroll
    for (int nt = 0; nt < 4; ++nt) o[nt] = (f32x4){0.f, 0.f, 0.f, 0.f};

    #pragma unroll
    for (int kt = 0; kt < 12; ++kt) {
        const unsigned* pa = (kt < 6) ? pku0[2 * kt]     : pku1[2 * kt - 12];
        const unsigned* pb = (kt < 6) ? pku0[2 * kt + 1] : pku1[2 * kt - 11];
        int a0 = __shfl((int)pa[0], lA, 64);
        int a1 = __shfl((int)pa[1], lA, 64);
        int a2 = __shfl((int)pa[0], lB, 64);
        int a3 = __shfl((int)pa[1], lB, 64);
        int b0 = __shfl((int)pb[0], lA, 64);
        int b1 = __shfl((int)pb[1], lA, 64);
        int b2 = __shfl((int)pb[0], lB, 64);
        int b3 = __shfl((int)pb[1], lB, 64);
        i32x4 wi;
        wi[0] = hi_ ? b0 : a0;
        wi[1] = hi_ ? b1 : a1;
        wi[2] = hi_ ? b2 : a2;
        wi[3] = hi_ ? b3 : a3;
        bf16x8 af = *(bf16x8*)&wi;

        // attn_w for j = kt*32 + 8g + 0..7 of row tl (aligned f32x4 when interior)
        {
            float pv_[8];
            #pragma unroll
            for (int p = 0; p < 4; ++p) {
                unsigned u = (unsigned)wi[p];
                pv_[2 * p]     = ubits_lo(u);
                pv_[2 * p + 1] = ubits_hi(u);
            }
            int c0 = kt * 32 + (g << 3) - tl;
            if (c0 >= 0 && c0 <= 2 * NW - 7) {
                f32x4 v0 = {pv_[0], pv_[1], pv_[2], pv_[3]};
                f32x4 v1 = {pv_[4], pv_[5], pv_[6], pv_[7]};
                *(f32x4*)&attw[awrow + c0] = v0;       // (awrow+c0) % 4 == 0
                *(f32x4*)&attw[awrow + c0 + 4] = v1;
            } else {
                #pragma unroll
                for (int e = 0; e < 8; ++e) {
                    int c = c0 + e;
                    if (c >= 0 && c <= 2 * NW)
                        attw[awrow + c] = pv_[e];
                }
            }
        }

        #pragma unroll
        for (int nt = 0; nt < 4; ++nt) {
            int c = kt * 4 + g;
            int phys = ((c & ~7) | ((c & 7) ^ (lr & 7))) << 3;
            bf16x8 bv = *(const bf16x8*)&kvs[(nt * 16 + lr) * 384 + phys];
            o[nt] = __builtin_amdgcn_mfma_f32_16x16x32_bf16(af, bv, o[nt], 0, 0, 0);
        }
    }

    // ---- x = src + context -> bf16 ----
    #pragma unroll
    for (int nt = 0; nt < 4; ++nt) {
        int d = nt * 16 + lr;
        int dcol = h * NHD + d;
        #pragma unroll
        for (int i = 0; i < 4; ++i) {
            int t = t0 + (g << 2) + i;
            long row = (long)b * NS + srow0 + t;
            float v = o[nt][i] + src[row * ND + dcol];
            xb[row * ND + dcol] = f2bf(v);
        }
    }
}

// ---------------- layernorm (in-place on y) ----------------
__global__ __launch_bounds__(256) void ln_kernel(float* __restrict__ y,
                                                 const float* __restrict__ g2,
                                                 const float* __restrict__ beta2) {
    int row = blockIdx.x;
    long base = (long)row * ND;
    int tid = threadIdx.x;
    float v[3];
    float s = 0.f, ss = 0.f;
    #pragma unroll
    for (int i = 0; i < 3; ++i) {
        v[i] = y[base + i * 256 + tid];
        s += v[i];
        ss += v[i] * v[i];
    }
    #pragma unroll
    for (int m = 1; m < 64; m <<= 1) {
        s += __shfl_xor(s, m, 64);
        ss += __shfl_xor(ss, m, 64);
    }
    __shared__ float red[8];
    int wid = tid >> 6, lane = tid & 63;
    if (lane == 0) { red[wid] = s; red[wid + 4] = ss; }
    __syncthreads();
    s = red[0] + red[1] + red[2] + red[3];
    ss = red[4] + red[5] + red[6] + red[7];
    float mu = s * (1.0f / ND);
    float var = ss * (1.0f / ND) - mu * mu;
    float rstd = rsqrtf(var + 1e-6f);
    #pragma unroll
    for (int i = 0; i < 3; ++i) {
        int c = i * 256 + tid;
        y[base + c] = g2[c] * (v[i] - mu) * rstd + beta2[c];
    }
}

extern "C" void kernel_launch(void* const* d_in, const int* in_sizes, int n_in,
                              void* d_out, int out_size, void* d_ws, size_t ws_size,
                              hipStream_t stream) {
    const float* src  = (const float*)d_in[0];
    const float* Wq   = (const float*)d_in[1];
    const float* bq   = (const float*)d_in[2];
    const float* Wk   = (const float*)d_in[3];
    const float* bk   = (const float*)d_in[4];
    const float* Wv   = (const float*)d_in[5];
    const float* bv   = (const float*)d_in[6];
    const float* W1   = (const float*)d_in[7];
    const float* b1   = (const float*)d_in[8];
    const float* W2   = (const float*)d_in[9];
    const float* b2   = (const float*)d_in[10];
    const float* g2   = (const float*)d_in[11];
    const float* bt2  = (const float*)d_in[12];

    float* out  = (float*)d_out;                       // y, then LN result in-place
    float* attw = out + (long)NB * NS * ND;

    char* ws = (char*)d_ws;
    const size_t SZ_XF  = (size_t)NB * NS * ND * 4;
    const size_t SZ_XB  = (size_t)NB * NS * ND * 2;
    const size_t SZ_W1T = (size_t)ND * NDFF * 2;
    const size_t SZ_W2T = (size_t)NDFF * ND * 2;
    const size_t SZ_QKV = (size_t)NB * NS * ND * 2;
    const size_t SZ_WT  = (size_t)ND * ND * 2;

    short* x_bf  = (short*)(ws + SZ_XF);
    short* W1T   = (short*)(ws + SZ_XF + SZ_XB);
    short* W2T   = (short*)(ws + SZ_XF + SZ_XB + SZ_W1T);
    char*  regA  = ws + SZ_XF + SZ_XB + SZ_W1T + SZ_W2T;
    short* srcb  = (short*)regA;
    short* WqT   = (short*)(regA + SZ_QKV);            // [2304][768] Wqkv^T contiguous
    short* qb    = (short*)(regA + SZ_QKV + 3 * SZ_WT);
    short* kb_   = (short*)(regA + 2 * SZ_QKV + 3 * SZ_WT);
    short* vb_   = (short*)(regA + 3 * SZ_QKV + 3 * SZ_WT);
    short* WkT   = WqT + (size_t)768 * ND;
    short* WvT   = WqT + (size_t)1536 * ND;
    short* hbuf  = (short*)regA;   // aliases srcb..vb_ (dead after attention)

    const int M = NB * NS;   // 8192

    // casts / transposes
    cast_bf16<<<(M * ND / 4 + 255) / 256, 256, 0, stream>>>(src, srcb, M * ND / 4);
    transpose_cast<<<dim3(ND / 32, ND / 32), 256, 0, stream>>>(Wq, WqT, ND, ND);
    transpose_cast<<<dim3(ND / 32, ND / 32), 256, 0, stream>>>(Wk, WkT, ND, ND);
    transpose_cast<<<dim3(ND / 32, ND / 32), 256, 0, stream>>>(Wv, WvT, ND, ND);
    transpose_cast<<<dim3(NDFF / 32, ND / 32), 256, 0, stream>>>(W1, W1T, ND, NDFF);
    transpose_cast<<<dim3(ND / 32, NDFF / 32), 256, 0, stream>>>(W2, W2T, NDFF, ND);

    // fused QKV projection (N = 2304 = q|k|v), grid 18*64 = 1152 (div by 8)
    gemmdb<4><<<(2304 / 128) * (M / 128), 256, 0, stream>>>(
        srcb, WqT, bq, bk, bv, qb, nullptr, M, 2304, ND, 2304 / 128);

    // band attention (static 48KB LDS)
    attn_kernel<<<NB * NH * NCH, 512, 0, stream>>>(qb, kb_, vb_, src, attw, x_bf);

    // FFN: grids 24*64 = 1536 and 6*64 = 384 (both div by 8)
    gemmdb<2><<<(NDFF / 128) * (M / 128), 256, 0, stream>>>(
        x_bf, W1T, b1, b1, b1, hbuf, nullptr, M, NDFF, ND, NDFF / 128);
    gemmdb<3><<<(ND / 128) * (M / 128), 256, 0, stream>>>(
        hbuf, W2T, b2, b2, b2, out, x_bf, M, ND, NDFF, ND / 128);

    // LayerNorm in-place
    ln_kernel<<<M, 256, 0, stream>>>(out, g2, bt2);
}